// Round 4
// baseline (805.635 us; speedup 1.0000x reference)
//
#include <hip/hip_runtime.h>

#define N_PTS 4096
#define B_SZ  8
#define M_OUT 1024
#define NS    64
#define CIN   128
#define COUT  256
// Worker blocks. Total grid = 8 + NW = 504 <= guaranteed residency capacity:
// LDS 53.76KB -> 3 blocks/CU fit (3*53760 <= 163840), 256 CUs -> >=512 slots.
// Every block is resident regardless of dispatch order, so the producer ->
// consumer polling below cannot deadlock (no ordering assumption).
#define NW    496
// Phase-B tiling: centers 0..959 as 8-center tiles (960 tiles, all hidden
// under the FPS window), centers 960..1023 as SINGLE-center tiles (512
// tiles) so the endgame is latency-parallel: the final centers (published in
// the last ~6us of FPS) are pooled by many blocks concurrently -> tail =
// ONE center's scan+pool (~5-15us), not a serial 8-center tile (~19us, R2).
#define NTILE_N 960
#define NTILE_T 1472

typedef float v2f __attribute__((ext_vector_type(2)));

// Wave-64 max reduce via DPP (row_shr 1/2/4/8, bcast15, bcast31), result
// broadcast through readlane(63). Bit-exact fmax tree. HW-VALIDATED (v2 776us,
// R6 738us, R8/R9 726us passing runs).
__device__ __forceinline__ float dpp_max_f32(float v) {
  int x = __builtin_bit_cast(int, v);
#define STG(C)                                                              \
  {                                                                         \
    int y = __builtin_amdgcn_update_dpp(x, x, C, 0xF, 0xF, false);          \
    float a = __builtin_bit_cast(float, x);                                 \
    float b2 = __builtin_bit_cast(float, y);                                \
    a = fmaxf(a, b2);                                                       \
    x = __builtin_bit_cast(int, a);                                         \
  }
  STG(0x111) STG(0x112) STG(0x114) STG(0x118) STG(0x142) STG(0x143)
#undef STG
  return __builtin_bit_cast(float, __builtin_amdgcn_readlane(x, 63));
}

// R4: SDMA-free state reset. hipMemsetAsync became an SDMA/blit graph node;
// the GFX->SDMA->GFX engine transitions cost ~60us/iter (gap was ~62us in
// R1-R3 regardless of node count, ~0 in memset-free R0). A 2us GFX kernel
// node avoids the engine switch. Re-executed every graph replay, so the
// re-poisoned-workspace hazard is still covered.
__global__ __launch_bounds__(256) void init_kernel(int* __restrict__ fps_idx) {
  // fps_idx[8192] = -1 (sentinel: unpublished); [8192] = gdone = -1.
  fps_idx[blockIdx.x * 256 + threadIdx.x] = -1;
  if (blockIdx.x == 0 && threadIdx.x == 0) fps_idx[B_SZ * M_OUT] = -1;
}

// ---------------------------------------------------------------------------
// Single persistent kernel (R2/R3-validated sync scheme: RELAXED agent-scope
// atomics to the coherent MALL as BOTH data and flag; zero fences on the FPS
// critical path; one-time gdone release/acquire for Z; endgame single-center
// tiles; dead final FPS step skipped).
// R4 deltas: (a) memset node -> init_kernel node (SDMA elimination),
// (b) normal-tile pollers back off s_sleep 8 -> 32 (4x less sc1 poll traffic;
// the 32ms rocprof-replay outlier in R3 showed ~90MB of poll fetch).
// ---------------------------------------------------------------------------
__global__ __launch_bounds__(256) void fused_kernel(
    const float* __restrict__ xyz, int* __restrict__ fps_idx,
    int* __restrict__ gdone, const float* __restrict__ F,
    const float* __restrict__ W, float* __restrict__ Z,
    const float* __restrict__ bias, const float* __restrict__ gamma,
    const float* __restrict__ beta, const float* __restrict__ rmean,
    const float* __restrict__ rvar, float* __restrict__ out) {
  __shared__ __align__(16) float smem[13360];
  if (blockIdx.x < 8) {
#pragma clang fp contract(off)
    __builtin_amdgcn_s_setprio(3);  // FPS is THE critical path (726us serial)
    // ---- FPS (R6-validated; math/order untouched) ----
    float* lx = smem;                         // [4096]
    float* ly = smem + 4096;                  // [4096]
    float* lz = smem + 8192;                  // [4096]
    float4 (*sl)[4] = (float4(*)[4])(smem + 12288);  // [2][4]
    int (*siw)[4] = (int(*)[4])(smem + 12320);       // [2][4]
    const int b = blockIdx.x, t = threadIdx.x;
    const int lane = t & 63, wv = t >> 6;
    const float* base = xyz + b * N_PTS * 3;
    for (int e = t; e < N_PTS; e += 256) {
      lx[e] = base[e * 3 + 0];
      ly[e] = base[e * 3 + 1];
      lz[e] = base[e * 3 + 2];
    }
    __syncthreads();
    const int nb = t * 16;  // contiguous: thread t owns [16t, 16t+16)
    v2f px[8], py[8], pz[8], m2[8];
#pragma unroll
    for (int j = 0; j < 8; ++j) {
      int n0 = nb + 2 * j;
      px[j] = (v2f){lx[n0], lx[n0 + 1]};
      py[j] = (v2f){ly[n0], ly[n0 + 1]};
      pz[j] = (v2f){lz[n0], lz[n0 + 1]};
      m2[j] = (v2f){1e10f, 1e10f};
    }
    int cur = 0;
    float cx = lx[0], cy = ly[0], cz = lz[0];
    for (int i = 0; i < M_OUT; ++i) {
      // Progressive publish: relaxed agent atomic (sc1 -> MALL, coherent
      // cross-XCD). Fire-and-forget: no waitcnt, no fence, no L2 writeback.
      if (t == 0)
        __hip_atomic_store(fps_idx + b * M_OUT + i, cur, __ATOMIC_RELAXED,
                           __HIP_MEMORY_SCOPE_AGENT);
      if (i == M_OUT - 1) break;  // last index published; its distance pass
                                  // is dead work (would only compute idx 1024)
      float bv = -1.0f;
      int bj = 0;
#pragma unroll
      for (int j = 0; j < 8; ++j) {
        v2f dx = px[j] - cx, dy = py[j] - cy, dz = pz[j] - cz;
        v2f d = dx * dx + dy * dy;  // contract(off): numpy op order, no FMA
        d = d + dz * dz;
        v2f md = __builtin_elementwise_min(m2[j], d);
        m2[j] = md;
        // ascending j, strict > => lowest tied index within the thread
        if (md.x > bv) { bv = md.x; bj = 2 * j; }
        if (md.y > bv) { bv = md.y; bj = 2 * j + 1; }
      }
      const float mv = dpp_max_f32(bv);  // wave max, all lanes (validated)
      unsigned long long tied = __ballot(bv == mv);  // non-empty
      const int fl = __ffsll(tied) - 1;              // first tied lane
      const int bi = nb + bj;
      const int widx = __builtin_amdgcn_readlane(bi, fl);
      // Pre-barrier uniform LDS broadcast read; hides in barrier skew.
      const float wx = lx[widx], wy = ly[widx], wz = lz[widx];
      const int p = i & 1;
      if (lane == 0) {
        sl[p][wv] = make_float4(mv, wx, wy, wz);
        siw[p][wv] = widx;
      }
      __syncthreads();  // the only barrier per step (parity-buffered slots)
      float4 s0 = sl[p][0], s1 = sl[p][1], s2 = sl[p][2], s3 = sl[p][3];
      int i0 = siw[p][0], i1 = siw[p][1], i2 = siw[p][2], i3 = siw[p][3];
      float gv = s0.x, gx = s0.y, gy = s0.z, gz = s0.w;
      int gi = i0;
      bool bt;
      bt = (s1.x > gv) || (s1.x == gv && i1 < gi);
      if (bt) { gv = s1.x; gi = i1; gx = s1.y; gy = s1.z; gz = s1.w; }
      bt = (s2.x > gv) || (s2.x == gv && i2 < gi);
      if (bt) { gv = s2.x; gi = i2; gx = s2.y; gy = s2.z; gz = s2.w; }
      bt = (s3.x > gv) || (s3.x == gv && i3 < gi);
      if (bt) { gv = s3.x; gi = i3; gx = s3.y; gy = s3.z; gz = s3.w; }
      cur = gi; cx = gx; cy = gy; cz = gz;
    }
  } else {
    const int w = blockIdx.x - 8;  // 0..NW-1
    // ---- phase A: conv tiles, grid-stride (R8-validated math) ----
    // Z[b][n][o] = sum_c F[b][c][n] * W[o][c]
    {
      float (*Bs)[68] = (float(*)[68])smem;          // [128][68]
      float (*As)[68] = (float(*)[68])(smem + 8704); // [32][68]
      const int tid = threadIdx.x;
      const int tx = tid & 15, ty = tid >> 4;
      for (int tile = w; tile < 2048; tile += NW) {
        __syncthreads();  // prev tile's As/Bs readers done before refill
        const int n0 = (tile & 63) * 64;
        const int o0 = ((tile >> 6) & 3) * 64;
        const int bb = tile >> 8;
        for (int l = 0; l < 32; ++l) {
          int e = l * 256 + tid;
          int c = e & 127, oo = e >> 7;
          Bs[c][oo] = W[(o0 + oo) * CIN + c];
        }
        float acc[4][4] = {};
        const float* Fb = F + bb * CIN * N_PTS;
        for (int c0 = 0; c0 < CIN; c0 += 32) {
          __syncthreads();
          for (int l = 0; l < 8; ++l) {
            int e = l * 256 + tid;
            int nn = e & 63, cc = e >> 6;
            As[cc][nn] = Fb[(c0 + cc) * N_PTS + n0 + nn];
          }
          __syncthreads();
#pragma unroll
          for (int cc = 0; cc < 32; ++cc) {
            float4 a = *(const float4*)&As[cc][tx * 4];
            float4 w4 = *(const float4*)&Bs[c0 + cc][ty * 4];
            acc[0][0] += a.x * w4.x; acc[0][1] += a.x * w4.y; acc[0][2] += a.x * w4.z; acc[0][3] += a.x * w4.w;
            acc[1][0] += a.y * w4.x; acc[1][1] += a.y * w4.y; acc[1][2] += a.y * w4.z; acc[1][3] += a.y * w4.w;
            acc[2][0] += a.z * w4.x; acc[2][1] += a.z * w4.y; acc[2][2] += a.z * w4.z; acc[2][3] += a.z * w4.w;
            acc[3][0] += a.w * w4.x; acc[3][1] += a.w * w4.y; acc[3][2] += a.w * w4.z; acc[3][3] += a.w * w4.w;
          }
        }
        float* Zb = Z + (size_t)(bb * N_PTS + n0) * COUT + o0;
#pragma unroll
        for (int i2 = 0; i2 < 4; ++i2) {
          int nn = tx * 4 + i2;
          float4 v = make_float4(acc[i2][0], acc[i2][1], acc[i2][2], acc[i2][3]);
          *(float4*)&Zb[(size_t)nn * COUT + ty * 4] = v;
        }
      }
    }
    // ONE-TIME Z handoff (off the FPS critical path): barrier drains each
    // wave's Z stores (vmcnt(0)); release-add writes back this XCD's L2 so Z
    // is agent-visible; consumers below acquire-invalidate ONCE.
    // gdone: init -1 by init_kernel, full count = NW-1.
    __syncthreads();
    if (threadIdx.x == 0)
      __hip_atomic_fetch_add(gdone, 1, __ATOMIC_RELEASE,
                             __HIP_MEMORY_SCOPE_AGENT);
    if (threadIdx.x == 0) {
      while (__hip_atomic_load(gdone, __ATOMIC_ACQUIRE,
                               __HIP_MEMORY_SCOPE_AGENT) < NW - 1)
        __builtin_amdgcn_s_sleep(16);
    }
    __syncthreads();
    __builtin_amdgcn_fence(__ATOMIC_ACQUIRE, "agent");  // Z now coherent
    // ---- phase B: ballq + gather/max/BN/ReLU, grid-stride ----
    // Per-tile gate: poll the needed fps_idx entries (relaxed agent loads,
    // sc1 from MALL; NO fence, NO L2 invalidation -> xyz/Z stay L2-hot).
    const int lane = threadIdx.x & 63, wv = threadIdx.x >> 6;
    const int o = threadIdx.x;  // 0..255
    const float sc = gamma[o] * (1.0f / sqrtf(rvar[o] + 1e-5f));
    const float bo = bias[o], mo = rmean[o], bt = beta[o];
    float (*T)[9] = (float(*)[9])smem;        // [256][9] floats
    int* sidx = (int*)(smem + 2304);          // [8*NS]
    int* cctr = (int*)(smem + 2816);          // [8] center indices
    for (int tb = w; tb < NTILE_T; tb += NW) {
      if (tb < NTILE_N) {
        // ======== normal 8-center tile (R2-validated path) ========
        const int b = tb & 7;
        const int m0 = (tb >> 3) * 8;
        if (threadIdx.x == 0) {
          int got;
          do {
            got = 1;
#pragma unroll
            for (int c = 0; c < 8; ++c) {
              int v = __hip_atomic_load(fps_idx + b * M_OUT + m0 + c,
                                        __ATOMIC_RELAXED,
                                        __HIP_MEMORY_SCOPE_AGENT);
              cctr[c] = v;
              got &= (v != -1);
            }
            // Coarse backoff: normal tiles have 100s of us of slack; 4x
            // lower sc1 poll rate than R3 (outlier had ~90MB poll fetch).
            if (!got) __builtin_amdgcn_s_sleep(32);
          } while (!got);
        }
        __syncthreads();  // broadcast cctr; orders prev tile's T/sidx reuse
        const float* base = xyz + b * N_PTS * 3;
        {
#pragma clang fp contract(off)
          for (int c = wv; c < 8; c += 4) {
            const int cidx = cctr[c];
            const float cx = base[cidx * 3 + 0], cy = base[cidx * 3 + 1],
                        cz = base[cidx * 3 + 2];
            int* srow = sidx + c * NS;
            int cnt = 0, first = 0;
            for (int ch = 0; ch < N_PTS / 64 && cnt < NS; ++ch) {
              const int n = ch * 64 + lane;
              float dx = base[n * 3 + 0] - cx;
              float dy = base[n * 3 + 1] - cy;
              float dz = base[n * 3 + 2] - cz;
              float d = dx * dx + dy * dy;
              d = d + dz * dz;
              const bool inb = d < 0.1024f;  // f32(RADIUS^2)
              unsigned long long mask = __ballot(inb);
              if (cnt == 0 && mask) first = ch * 64 + (__ffsll(mask) - 1);
              const int pos = cnt + __popcll(mask & ((1ull << lane) - 1ull));
              if (inb && pos < NS) srow[pos] = n;
              cnt += (int)__popcll(mask);
            }
            if (lane >= cnt) srow[lane] = first;  // pad (center => cnt >= 1)
          }
        }
        __syncthreads();
        const float* Zb = Z + (size_t)b * N_PTS * COUT;
        for (int mi = 0; mi < 8; ++mi) {
          float c0 = -1e30f, c1 = -1e30f, c2 = -1e30f, c3 = -1e30f;
          float c4 = -1e30f, c5 = -1e30f, c6 = -1e30f, c7 = -1e30f;
#pragma unroll
          for (int s = 0; s < NS; s += 8) {
            int4 iv0 = *(const int4*)&sidx[mi * NS + s];
            int4 iv1 = *(const int4*)&sidx[mi * NS + s + 4];
            c0 = fmaxf(c0, Zb[(size_t)iv0.x * COUT + o]);
            c1 = fmaxf(c1, Zb[(size_t)iv0.y * COUT + o]);
            c2 = fmaxf(c2, Zb[(size_t)iv0.z * COUT + o]);
            c3 = fmaxf(c3, Zb[(size_t)iv0.w * COUT + o]);
            c4 = fmaxf(c4, Zb[(size_t)iv1.x * COUT + o]);
            c5 = fmaxf(c5, Zb[(size_t)iv1.y * COUT + o]);
            c6 = fmaxf(c6, Zb[(size_t)iv1.z * COUT + o]);
            c7 = fmaxf(c7, Zb[(size_t)iv1.w * COUT + o]);
          }
          float best = fmaxf(fmaxf(fmaxf(c0, c1), fmaxf(c2, c3)),
                             fmaxf(fmaxf(c4, c5), fmaxf(c6, c7)));
          float tv = best + bo;
          tv = (tv - mo) * sc + bt;
          T[o][mi] = fmaxf(tv, 0.0f);  // distinct (o,mi): race-free
        }
        __syncthreads();
        for (int l = 0; l < 8; ++l) {
          int e = l * 256 + (int)threadIdx.x;
          int mm = e & 7, oo = e >> 3;
          out[(size_t)(b * COUT + oo) * M_OUT + m0 + mm] = T[oo][mm];
        }
      } else {
        // ======== endgame single-center tile (tail de-latencied) ========
        const int k = tb - NTILE_N;     // 0..511
        const int b = k & 7;
        const int m = 960 + (k >> 3);   // 960..1023
        if (threadIdx.x == 0) {
          int v;
          while ((v = __hip_atomic_load(fps_idx + b * M_OUT + m,
                                        __ATOMIC_RELAXED,
                                        __HIP_MEMORY_SCOPE_AGENT)) == -1)
            __builtin_amdgcn_s_sleep(2);  // fine wake: this IS the tail
          cctr[0] = v;
        }
        __syncthreads();  // broadcast; also orders prev tile's sidx reuse
        const float* base = xyz + b * N_PTS * 3;
        if (wv == 0) {  // identical per-center scan, wave 0 only
#pragma clang fp contract(off)
          const int cidx = cctr[0];
          const float cx = base[cidx * 3 + 0], cy = base[cidx * 3 + 1],
                      cz = base[cidx * 3 + 2];
          int cnt = 0, first = 0;
          for (int ch = 0; ch < N_PTS / 64 && cnt < NS; ++ch) {
            const int n = ch * 64 + lane;
            float dx = base[n * 3 + 0] - cx;
            float dy = base[n * 3 + 1] - cy;
            float dz = base[n * 3 + 2] - cz;
            float d = dx * dx + dy * dy;
            d = d + dz * dz;
            const bool inb = d < 0.1024f;  // f32(RADIUS^2)
            unsigned long long mask = __ballot(inb);
            if (cnt == 0 && mask) first = ch * 64 + (__ffsll(mask) - 1);
            const int pos = cnt + __popcll(mask & ((1ull << lane) - 1ull));
            if (inb && pos < NS) sidx[pos] = n;
            cnt += (int)__popcll(mask);
          }
          if (lane >= cnt) sidx[lane] = first;  // pad (center => cnt >= 1)
        }
        __syncthreads();
        // pool: identical 8-chain structure per (o, m) => bit-identical
        const float* Zb = Z + (size_t)b * N_PTS * COUT;
        float c0 = -1e30f, c1 = -1e30f, c2 = -1e30f, c3 = -1e30f;
        float c4 = -1e30f, c5 = -1e30f, c6 = -1e30f, c7 = -1e30f;
#pragma unroll
        for (int s = 0; s < NS; s += 8) {
          int4 iv0 = *(const int4*)&sidx[s];
          int4 iv1 = *(const int4*)&sidx[s + 4];
          c0 = fmaxf(c0, Zb[(size_t)iv0.x * COUT + o]);
          c1 = fmaxf(c1, Zb[(size_t)iv0.y * COUT + o]);
          c2 = fmaxf(c2, Zb[(size_t)iv0.z * COUT + o]);
          c3 = fmaxf(c3, Zb[(size_t)iv0.w * COUT + o]);
          c4 = fmaxf(c4, Zb[(size_t)iv1.x * COUT + o]);
          c5 = fmaxf(c5, Zb[(size_t)iv1.y * COUT + o]);
          c6 = fmaxf(c6, Zb[(size_t)iv1.z * COUT + o]);
          c7 = fmaxf(c7, Zb[(size_t)iv1.w * COUT + o]);
        }
        float best = fmaxf(fmaxf(fmaxf(c0, c1), fmaxf(c2, c3)),
                           fmaxf(fmaxf(c4, c5), fmaxf(c6, c7)));
        float tv = best + bo;
        tv = (tv - mo) * sc + bt;
        out[(size_t)(b * COUT + o) * M_OUT + m] = fmaxf(tv, 0.0f);
      }
    }
  }
}

extern "C" void kernel_launch(void* const* d_in, const int* in_sizes, int n_in,
                              void* d_out, int out_size, void* d_ws, size_t ws_size,
                              hipStream_t stream) {
  const float* xyz      = (const float*)d_in[0];
  const float* features = (const float*)d_in[1];
  const float* W        = (const float*)d_in[2];
  const float* bias     = (const float*)d_in[3];
  const float* gamma    = (const float*)d_in[4];
  const float* beta     = (const float*)d_in[5];
  const float* rmean    = (const float*)d_in[6];
  const float* rvar     = (const float*)d_in[7];
  float* out = (float*)d_out;

  char* ws = (char*)d_ws;
  int* fps   = (int*)ws;                                 // 32 KB
  int* gdone = fps + B_SZ * M_OUT;                       // right after fps_idx
  float* Z   = (float*)(ws + (64 << 10) + (2 << 20));    // 33.5 MB

  // GFX kernel node instead of SDMA memset: fps_idx sentinel (-1 =
  // unpublished) and gdone (-1; complete at NW-1). Re-executed every graph
  // replay -> re-poisoned workspace is still re-initialized each run.
  init_kernel<<<32, 256, 0, stream>>>(fps);
  fused_kernel<<<8 + NW, 256, 0, stream>>>(
      xyz, fps, gdone, features, W, Z, bias, gamma, beta, rmean, rvar, out);
}

// Round 5
// 801.836 us; speedup vs baseline: 1.0047x; 1.0047x over previous
//
#include <hip/hip_runtime.h>

#define N_PTS 4096
#define B_SZ  8
#define M_OUT 1024
#define NS    64
#define CIN   128
#define COUT  256
// Worker blocks. Total grid = 8 + NW = 504 <= guaranteed residency capacity:
// LDS 53.76KB -> 3 blocks/CU fit (3*53760 <= 163840), 256 CUs -> >=512 slots.
// Every block is resident regardless of dispatch order, so the producer ->
// consumer polling below cannot deadlock (no ordering assumption).
#define NW    496
// Phase-B tiling: centers 0..959 as 8-center tiles (960 tiles, all hidden
// under the FPS window), centers 960..1023 as SINGLE-center tiles (512
// tiles) so the endgame is latency-parallel.
#define NTILE_N 960
#define NTILE_T 1472

typedef float v2f __attribute__((ext_vector_type(2)));

// Wave-64 max reduce via DPP (row_shr 1/2/4/8, bcast15, bcast31), result
// broadcast through readlane(63). Bit-exact fmax tree. HW-VALIDATED (v2 776us,
// R6 738us, R8/R9 726us passing runs).
__device__ __forceinline__ float dpp_max_f32(float v) {
  int x = __builtin_bit_cast(int, v);
#define STG(C)                                                              \
  {                                                                         \
    int y = __builtin_amdgcn_update_dpp(x, x, C, 0xF, 0xF, false);          \
    float a = __builtin_bit_cast(float, x);                                 \
    float b2 = __builtin_bit_cast(float, y);                                \
    a = fmaxf(a, b2);                                                       \
    x = __builtin_bit_cast(int, a);                                         \
  }
  STG(0x111) STG(0x112) STG(0x114) STG(0x118) STG(0x142) STG(0x143)
#undef STG
  return __builtin_bit_cast(float, __builtin_amdgcn_readlane(x, 63));
}

// LDS-only workgroup barrier: s_waitcnt lgkmcnt(0) + s_barrier, WITHOUT the
// vmcnt(0) drain __syncthreads() implies. In the FPS loop wave 0 carries an
// outstanding relaxed sc1 publish store each step; a full __syncthreads()
// would make every wave wait for that MALL ack every step. The slot handoff
// is pure LDS -> lgkmcnt suffices. sched_barrier(0) pins ds ops on both
// sides (rule: compiler may move mem ops across inline-asm waitcnt).
__device__ __forceinline__ void lds_barrier() {
  __builtin_amdgcn_sched_barrier(0);
  asm volatile("s_waitcnt lgkmcnt(0)" ::: "memory");
  __builtin_amdgcn_sched_barrier(0);
  __builtin_amdgcn_s_barrier();
  __builtin_amdgcn_sched_barrier(0);
}

// R4-validated: GFX init kernel node (no SDMA). Re-executed every graph
// replay, so a re-poisoned workspace is re-initialized each run.
__global__ __launch_bounds__(256) void init_kernel(int* __restrict__ fps_idx) {
  // fps_idx[0..8191] = -1 (sentinel: unpublished); [8192] = gdone = -1.
  fps_idx[blockIdx.x * 256 + threadIdx.x] = -1;
  if (blockIdx.x == 0 && threadIdx.x == 0) fps_idx[B_SZ * M_OUT] = -1;
}

// ---------------------------------------------------------------------------
// Single persistent kernel (R2/R3/R4-validated sync scheme: RELAXED agent
// atomics to the coherent MALL as BOTH data and flag; zero fences on the FPS
// critical path; one-time gdone release/acquire for Z; endgame single-center
// tiles; dead final FPS step skipped; GFX init node).
// R5 deltas (both bit-exact):
//  (a) in-loop __syncthreads -> lds_barrier(): removes the per-step vmcnt(0)
//      wait on the sc1 publish store (publish stays in flight across the
//      barrier, counted-vmcnt style).
//  (b) 4-slot combine cascade -> 2-level tree: lexicographic (v,idx) argmax
//      is a total order => associative => tree == cascade, dependent-chain
//      depth ~96 -> ~64 cyc per step.
// ---------------------------------------------------------------------------
__global__ __launch_bounds__(256) void fused_kernel(
    const float* __restrict__ xyz, int* __restrict__ fps_idx,
    int* __restrict__ gdone, const float* __restrict__ F,
    const float* __restrict__ W, float* __restrict__ Z,
    const float* __restrict__ bias, const float* __restrict__ gamma,
    const float* __restrict__ beta, const float* __restrict__ rmean,
    const float* __restrict__ rvar, float* __restrict__ out) {
  __shared__ __align__(16) float smem[13360];
  if (blockIdx.x < 8) {
#pragma clang fp contract(off)
    __builtin_amdgcn_s_setprio(3);  // FPS is THE critical path (726us serial)
    // ---- FPS (R6-validated; math/order untouched) ----
    float* lx = smem;                         // [4096]
    float* ly = smem + 4096;                  // [4096]
    float* lz = smem + 8192;                  // [4096]
    float4 (*sl)[4] = (float4(*)[4])(smem + 12288);  // [2][4]
    int (*siw)[4] = (int(*)[4])(smem + 12320);       // [2][4]
    const int b = blockIdx.x, t = threadIdx.x;
    const int lane = t & 63, wv = t >> 6;
    const float* base = xyz + b * N_PTS * 3;
    for (int e = t; e < N_PTS; e += 256) {
      lx[e] = base[e * 3 + 0];
      ly[e] = base[e * 3 + 1];
      lz[e] = base[e * 3 + 2];
    }
    __syncthreads();  // staging barrier: keep the full drain here
    const int nb = t * 16;  // contiguous: thread t owns [16t, 16t+16)
    v2f px[8], py[8], pz[8], m2[8];
#pragma unroll
    for (int j = 0; j < 8; ++j) {
      int n0 = nb + 2 * j;
      px[j] = (v2f){lx[n0], lx[n0 + 1]};
      py[j] = (v2f){ly[n0], ly[n0 + 1]};
      pz[j] = (v2f){lz[n0], lz[n0 + 1]};
      m2[j] = (v2f){1e10f, 1e10f};
    }
    int cur = 0;
    float cx = lx[0], cy = ly[0], cz = lz[0];
    for (int i = 0; i < M_OUT; ++i) {
      // Progressive publish: relaxed agent atomic (sc1 -> MALL, coherent
      // cross-XCD). Fire-and-forget: no waitcnt, no fence, no L2 writeback.
      // With lds_barrier below, this store stays in flight across the step
      // boundary instead of being drained by a vmcnt(0).
      if (t == 0)
        __hip_atomic_store(fps_idx + b * M_OUT + i, cur, __ATOMIC_RELAXED,
                           __HIP_MEMORY_SCOPE_AGENT);
      if (i == M_OUT - 1) break;  // last index published; its distance pass
                                  // is dead work (would only compute idx 1024)
      float bv = -1.0f;
      int bj = 0;
#pragma unroll
      for (int j = 0; j < 8; ++j) {
        v2f dx = px[j] - cx, dy = py[j] - cy, dz = pz[j] - cz;
        v2f d = dx * dx + dy * dy;  // contract(off): numpy op order, no FMA
        d = d + dz * dz;
        v2f md = __builtin_elementwise_min(m2[j], d);
        m2[j] = md;
        // ascending j, strict > => lowest tied index within the thread
        if (md.x > bv) { bv = md.x; bj = 2 * j; }
        if (md.y > bv) { bv = md.y; bj = 2 * j + 1; }
      }
      const float mv = dpp_max_f32(bv);  // wave max, all lanes (validated)
      unsigned long long tied = __ballot(bv == mv);  // non-empty
      const int fl = __ffsll(tied) - 1;              // first tied lane
      const int bi = nb + bj;
      const int widx = __builtin_amdgcn_readlane(bi, fl);
      // Pre-barrier uniform LDS broadcast read; hides in barrier skew.
      const float wx = lx[widx], wy = ly[widx], wz = lz[widx];
      const int p = i & 1;
      if (lane == 0) {
        sl[p][wv] = make_float4(mv, wx, wy, wz);
        siw[p][wv] = widx;
      }
      lds_barrier();  // the only barrier per step (parity-buffered slots)
      float4 s0 = sl[p][0], s1 = sl[p][1], s2 = sl[p][2], s3 = sl[p][3];
      int i0 = siw[p][0], i1 = siw[p][1], i2 = siw[p][2], i3 = siw[p][3];
      // 2-level tree reduce of the total order (max v, tie -> min idx).
      // Associative => identical winner to the validated 3-step cascade.
      bool t01 = (s1.x > s0.x) || (s1.x == s0.x && i1 < i0);
      float4 w01 = t01 ? s1 : s0;
      int j01 = t01 ? i1 : i0;
      bool t23 = (s3.x > s2.x) || (s3.x == s2.x && i3 < i2);
      float4 w23 = t23 ? s3 : s2;
      int j23 = t23 ? i3 : i2;
      bool tf = (w23.x > w01.x) || (w23.x == w01.x && j23 < j01);
      float4 wf = tf ? w23 : w01;
      cur = tf ? j23 : j01;
      cx = wf.y; cy = wf.z; cz = wf.w;
    }
  } else {
    const int w = blockIdx.x - 8;  // 0..NW-1
    // ---- phase A: conv tiles, grid-stride (R8-validated math) ----
    // Z[b][n][o] = sum_c F[b][c][n] * W[o][c]
    {
      float (*Bs)[68] = (float(*)[68])smem;          // [128][68]
      float (*As)[68] = (float(*)[68])(smem + 8704); // [32][68]
      const int tid = threadIdx.x;
      const int tx = tid & 15, ty = tid >> 4;
      for (int tile = w; tile < 2048; tile += NW) {
        __syncthreads();  // prev tile's As/Bs readers done before refill
        const int n0 = (tile & 63) * 64;
        const int o0 = ((tile >> 6) & 3) * 64;
        const int bb = tile >> 8;
        for (int l = 0; l < 32; ++l) {
          int e = l * 256 + tid;
          int c = e & 127, oo = e >> 7;
          Bs[c][oo] = W[(o0 + oo) * CIN + c];
        }
        float acc[4][4] = {};
        const float* Fb = F + bb * CIN * N_PTS;
        for (int c0 = 0; c0 < CIN; c0 += 32) {
          __syncthreads();
          for (int l = 0; l < 8; ++l) {
            int e = l * 256 + tid;
            int nn = e & 63, cc = e >> 6;
            As[cc][nn] = Fb[(c0 + cc) * N_PTS + n0 + nn];
          }
          __syncthreads();
#pragma unroll
          for (int cc = 0; cc < 32; ++cc) {
            float4 a = *(const float4*)&As[cc][tx * 4];
            float4 w4 = *(const float4*)&Bs[c0 + cc][ty * 4];
            acc[0][0] += a.x * w4.x; acc[0][1] += a.x * w4.y; acc[0][2] += a.x * w4.z; acc[0][3] += a.x * w4.w;
            acc[1][0] += a.y * w4.x; acc[1][1] += a.y * w4.y; acc[1][2] += a.y * w4.z; acc[1][3] += a.y * w4.w;
            acc[2][0] += a.z * w4.x; acc[2][1] += a.z * w4.y; acc[2][2] += a.z * w4.z; acc[2][3] += a.z * w4.w;
            acc[3][0] += a.w * w4.x; acc[3][1] += a.w * w4.y; acc[3][2] += a.w * w4.z; acc[3][3] += a.w * w4.w;
          }
        }
        float* Zb = Z + (size_t)(bb * N_PTS + n0) * COUT + o0;
#pragma unroll
        for (int i2 = 0; i2 < 4; ++i2) {
          int nn = tx * 4 + i2;
          float4 v = make_float4(acc[i2][0], acc[i2][1], acc[i2][2], acc[i2][3]);
          *(float4*)&Zb[(size_t)nn * COUT + ty * 4] = v;
        }
      }
    }
    // ONE-TIME Z handoff (off the FPS critical path): barrier drains each
    // wave's Z stores (vmcnt(0)); release-add writes back this XCD's L2 so Z
    // is agent-visible; consumers below acquire-invalidate ONCE.
    // gdone: init -1 by init_kernel, full count = NW-1.
    __syncthreads();
    if (threadIdx.x == 0)
      __hip_atomic_fetch_add(gdone, 1, __ATOMIC_RELEASE,
                             __HIP_MEMORY_SCOPE_AGENT);
    if (threadIdx.x == 0) {
      while (__hip_atomic_load(gdone, __ATOMIC_ACQUIRE,
                               __HIP_MEMORY_SCOPE_AGENT) < NW - 1)
        __builtin_amdgcn_s_sleep(16);
    }
    __syncthreads();
    __builtin_amdgcn_fence(__ATOMIC_ACQUIRE, "agent");  // Z now coherent
    // ---- phase B: ballq + gather/max/BN/ReLU, grid-stride ----
    // Per-tile gate: poll the needed fps_idx entries (relaxed agent loads,
    // sc1 from MALL; NO fence, NO L2 invalidation -> xyz/Z stay L2-hot).
    const int lane = threadIdx.x & 63, wv = threadIdx.x >> 6;
    const int o = threadIdx.x;  // 0..255
    const float sc = gamma[o] * (1.0f / sqrtf(rvar[o] + 1e-5f));
    const float bo = bias[o], mo = rmean[o], bt = beta[o];
    float (*T)[9] = (float(*)[9])smem;        // [256][9] floats
    int* sidx = (int*)(smem + 2304);          // [8*NS]
    int* cctr = (int*)(smem + 2816);          // [8] center indices
    for (int tb = w; tb < NTILE_T; tb += NW) {
      if (tb < NTILE_N) {
        // ======== normal 8-center tile (R2-validated path) ========
        const int b = tb & 7;
        const int m0 = (tb >> 3) * 8;
        if (threadIdx.x == 0) {
          int got;
          do {
            got = 1;
#pragma unroll
            for (int c = 0; c < 8; ++c) {
              int v = __hip_atomic_load(fps_idx + b * M_OUT + m0 + c,
                                        __ATOMIC_RELAXED,
                                        __HIP_MEMORY_SCOPE_AGENT);
              cctr[c] = v;
              got &= (v != -1);
            }
            // Coarse backoff: normal tiles have 100s of us of slack.
            if (!got) __builtin_amdgcn_s_sleep(32);
          } while (!got);
        }
        __syncthreads();  // broadcast cctr; orders prev tile's T/sidx reuse
        const float* base = xyz + b * N_PTS * 3;
        {
#pragma clang fp contract(off)
          for (int c = wv; c < 8; c += 4) {
            const int cidx = cctr[c];
            const float cx = base[cidx * 3 + 0], cy = base[cidx * 3 + 1],
                        cz = base[cidx * 3 + 2];
            int* srow = sidx + c * NS;
            int cnt = 0, first = 0;
            for (int ch = 0; ch < N_PTS / 64 && cnt < NS; ++ch) {
              const int n = ch * 64 + lane;
              float dx = base[n * 3 + 0] - cx;
              float dy = base[n * 3 + 1] - cy;
              float dz = base[n * 3 + 2] - cz;
              float d = dx * dx + dy * dy;
              d = d + dz * dz;
              const bool inb = d < 0.1024f;  // f32(RADIUS^2)
              unsigned long long mask = __ballot(inb);
              if (cnt == 0 && mask) first = ch * 64 + (__ffsll(mask) - 1);
              const int pos = cnt + __popcll(mask & ((1ull << lane) - 1ull));
              if (inb && pos < NS) srow[pos] = n;
              cnt += (int)__popcll(mask);
            }
            if (lane >= cnt) srow[lane] = first;  // pad (center => cnt >= 1)
          }
        }
        __syncthreads();
        const float* Zb = Z + (size_t)b * N_PTS * COUT;
        for (int mi = 0; mi < 8; ++mi) {
          float c0 = -1e30f, c1 = -1e30f, c2 = -1e30f, c3 = -1e30f;
          float c4 = -1e30f, c5 = -1e30f, c6 = -1e30f, c7 = -1e30f;
#pragma unroll
          for (int s = 0; s < NS; s += 8) {
            int4 iv0 = *(const int4*)&sidx[mi * NS + s];
            int4 iv1 = *(const int4*)&sidx[mi * NS + s + 4];
            c0 = fmaxf(c0, Zb[(size_t)iv0.x * COUT + o]);
            c1 = fmaxf(c1, Zb[(size_t)iv0.y * COUT + o]);
            c2 = fmaxf(c2, Zb[(size_t)iv0.z * COUT + o]);
            c3 = fmaxf(c3, Zb[(size_t)iv0.w * COUT + o]);
            c4 = fmaxf(c4, Zb[(size_t)iv1.x * COUT + o]);
            c5 = fmaxf(c5, Zb[(size_t)iv1.y * COUT + o]);
            c6 = fmaxf(c6, Zb[(size_t)iv1.z * COUT + o]);
            c7 = fmaxf(c7, Zb[(size_t)iv1.w * COUT + o]);
          }
          float best = fmaxf(fmaxf(fmaxf(c0, c1), fmaxf(c2, c3)),
                             fmaxf(fmaxf(c4, c5), fmaxf(c6, c7)));
          float tv = best + bo;
          tv = (tv - mo) * sc + bt;
          T[o][mi] = fmaxf(tv, 0.0f);  // distinct (o,mi): race-free
        }
        __syncthreads();
        for (int l = 0; l < 8; ++l) {
          int e = l * 256 + (int)threadIdx.x;
          int mm = e & 7, oo = e >> 3;
          out[(size_t)(b * COUT + oo) * M_OUT + m0 + mm] = T[oo][mm];
        }
      } else {
        // ======== endgame single-center tile (tail de-latencied) ========
        const int k = tb - NTILE_N;     // 0..511
        const int b = k & 7;
        const int m = 960 + (k >> 3);   // 960..1023
        if (threadIdx.x == 0) {
          int v;
          while ((v = __hip_atomic_load(fps_idx + b * M_OUT + m,
                                        __ATOMIC_RELAXED,
                                        __HIP_MEMORY_SCOPE_AGENT)) == -1)
            __builtin_amdgcn_s_sleep(2);  // fine wake: this IS the tail
          cctr[0] = v;
        }
        __syncthreads();  // broadcast; also orders prev tile's sidx reuse
        const float* base = xyz + b * N_PTS * 3;
        if (wv == 0) {  // identical per-center scan, wave 0 only
#pragma clang fp contract(off)
          const int cidx = cctr[0];
          const float cx = base[cidx * 3 + 0], cy = base[cidx * 3 + 1],
                      cz = base[cidx * 3 + 2];
          int cnt = 0, first = 0;
          for (int ch = 0; ch < N_PTS / 64 && cnt < NS; ++ch) {
            const int n = ch * 64 + lane;
            float dx = base[n * 3 + 0] - cx;
            float dy = base[n * 3 + 1] - cy;
            float dz = base[n * 3 + 2] - cz;
            float d = dx * dx + dy * dy;
            d = d + dz * dz;
            const bool inb = d < 0.1024f;  // f32(RADIUS^2)
            unsigned long long mask = __ballot(inb);
            if (cnt == 0 && mask) first = ch * 64 + (__ffsll(mask) - 1);
            const int pos = cnt + __popcll(mask & ((1ull << lane) - 1ull));
            if (inb && pos < NS) sidx[pos] = n;
            cnt += (int)__popcll(mask);
          }
          if (lane >= cnt) sidx[lane] = first;  // pad (center => cnt >= 1)
        }
        __syncthreads();
        // pool: identical 8-chain structure per (o, m) => bit-identical
        const float* Zb = Z + (size_t)b * N_PTS * COUT;
        float c0 = -1e30f, c1 = -1e30f, c2 = -1e30f, c3 = -1e30f;
        float c4 = -1e30f, c5 = -1e30f, c6 = -1e30f, c7 = -1e30f;
#pragma unroll
        for (int s = 0; s < NS; s += 8) {
          int4 iv0 = *(const int4*)&sidx[s];
          int4 iv1 = *(const int4*)&sidx[s + 4];
          c0 = fmaxf(c0, Zb[(size_t)iv0.x * COUT + o]);
          c1 = fmaxf(c1, Zb[(size_t)iv0.y * COUT + o]);
          c2 = fmaxf(c2, Zb[(size_t)iv0.z * COUT + o]);
          c3 = fmaxf(c3, Zb[(size_t)iv0.w * COUT + o]);
          c4 = fmaxf(c4, Zb[(size_t)iv1.x * COUT + o]);
          c5 = fmaxf(c5, Zb[(size_t)iv1.y * COUT + o]);
          c6 = fmaxf(c6, Zb[(size_t)iv1.z * COUT + o]);
          c7 = fmaxf(c7, Zb[(size_t)iv1.w * COUT + o]);
        }
        float best = fmaxf(fmaxf(fmaxf(c0, c1), fmaxf(c2, c3)),
                           fmaxf(fmaxf(c4, c5), fmaxf(c6, c7)));
        float tv = best + bo;
        tv = (tv - mo) * sc + bt;
        out[(size_t)(b * COUT + o) * M_OUT + m] = fmaxf(tv, 0.0f);
      }
    }
  }
}

extern "C" void kernel_launch(void* const* d_in, const int* in_sizes, int n_in,
                              void* d_out, int out_size, void* d_ws, size_t ws_size,
                              hipStream_t stream) {
  const float* xyz      = (const float*)d_in[0];
  const float* features = (const float*)d_in[1];
  const float* W        = (const float*)d_in[2];
  const float* bias     = (const float*)d_in[3];
  const float* gamma    = (const float*)d_in[4];
  const float* beta     = (const float*)d_in[5];
  const float* rmean    = (const float*)d_in[6];
  const float* rvar     = (const float*)d_in[7];
  float* out = (float*)d_out;

  char* ws = (char*)d_ws;
  int* fps   = (int*)ws;                                 // 32 KB
  int* gdone = fps + B_SZ * M_OUT;                       // right after fps_idx
  float* Z   = (float*)(ws + (64 << 10) + (2 << 20));    // 33.5 MB

  // GFX kernel node (no SDMA): fps_idx sentinel (-1 = unpublished) and gdone
  // (-1; complete at NW-1). Re-executed every graph replay.
  init_kernel<<<32, 256, 0, stream>>>(fps);
  fused_kernel<<<8 + NW, 256, 0, stream>>>(
      xyz, fps, gdone, features, W, Z, bias, gamma, beta, rmean, rvar, out);
}